// Round 4
// baseline (278.065 us; speedup 1.0000x reference)
//
#include <hip/hip_runtime.h>
#include <math.h>

#define D_PET 128
#define NK    256
#define NB    2048
#define NBATCH 16

__device__ __forceinline__ float silu(float x) {
    return x / (1.0f + expf(-x));
}

__device__ __forceinline__ int lower_bound_dev(const int* a, int n, int v) {
    int lo = 0, hi = n;
    while (lo < hi) {
        int m = (lo + hi) >> 1;
        if (a[m] < v) lo = m + 1; else hi = m;
    }
    return lo;
}

// ---------------------------------------------------------------------------
// Kernel 1 (fused): [0,512) MLP blocks, [512,2560) phase blocks,
// [2560,3072) zero-t2 blocks (t2 must be 0 for s_kernel's atomic adds).
// ---------------------------------------------------------------------------
#define MJ 8
#define MLP_BLOCKS (NBATCH * NK / MJ)       // 512
#define PHASE_BLOCKS NB                     // 2048
#define ZERO_BLOCKS 512
#define PREP_GRID (MLP_BLOCKS + PHASE_BLOCKS + ZERO_BLOCKS)

__global__ void __launch_bounds__(256) prep_kernel(
                           const float* __restrict__ kvec,
                           const float* __restrict__ W1, const float* __restrict__ b1,
                           const float* __restrict__ W2, const float* __restrict__ b2,
                           const float* __restrict__ W3, const float* __restrict__ b3,
                           float* __restrict__ filt,
                           const float* __restrict__ pos,
                           const int* __restrict__ batch,
                           float2* __restrict__ cs2,
                           float* __restrict__ t2f) {
    __shared__ float kv_s[MJ * 3];
    __shared__ float x_lds[D_PET * MJ];

    if (blockIdx.x >= MLP_BLOCKS + PHASE_BLOCKS) {
        // ---- zero t2: 512 blocks x 512 float4 ----
        int zi = blockIdx.x - (MLP_BLOCKS + PHASE_BLOCKS);
        float4* p = (float4*)t2f;
        float4 z = make_float4(0.f, 0.f, 0.f, 0.f);
        p[(size_t)zi * 512 + threadIdx.x]       = z;
        p[(size_t)zi * 512 + threadIdx.x + 256] = z;
        return;
    }
    if (blockIdx.x >= MLP_BLOCKS) {
        // ---- phase table ----
        int n = blockIdx.x - MLP_BLOCKS;
        int k = threadIdx.x;
        int b = batch[n];
        float p0 = pos[n * 3 + 0], p1 = pos[n * 3 + 1], p2 = pos[n * 3 + 2];
        const float* kv = kvec + ((size_t)b * NK + k) * 3;
        float ph = p0 * kv[0] + p1 * kv[1] + p2 * kv[2];
        float s, c;
        sincosf(ph, &s, &c);
        cs2[(size_t)n * NK + k] = make_float2(c, s);
        return;
    }

    // ---- MLP ----
    int bk0 = blockIdx.x * MJ;
    int d   = threadIdx.x & (D_PET - 1);
    int jg  = threadIdx.x >> 7;

    if (threadIdx.x < MJ * 3) kv_s[threadIdx.x] = kvec[bk0 * 3 + threadIdx.x];
    __syncthreads();

    float w10 = W1[0 * D_PET + d], w11 = W1[1 * D_PET + d], w12 = W1[2 * D_PET + d];
    float bb1 = b1[d];
    float4 x1;
    {
        float* xp = (float*)&x1;
#pragma unroll
        for (int i = 0; i < 4; i++) {
            int j = jg * 4 + i;
            float a = bb1;
            a = fmaf(kv_s[j * 3 + 0], w10, a);
            a = fmaf(kv_s[j * 3 + 1], w11, a);
            a = fmaf(kv_s[j * 3 + 2], w12, a);
            xp[i] = silu(a);
        }
    }
    *(float4*)&x_lds[(d << 3) + (jg << 2)] = x1;
    __syncthreads();

    float acc0 = b2[d], acc1 = acc0, acc2 = acc0, acc3 = acc0;
#pragma unroll
    for (int e0 = 0; e0 < D_PET; e0 += 8) {
        float w[8];
#pragma unroll
        for (int i = 0; i < 8; i++) w[i] = W2[(e0 + i) * D_PET + d];
        __builtin_amdgcn_sched_barrier(0);
#pragma unroll
        for (int i = 0; i < 8; i++) {
            float4 xv = *(const float4*)&x_lds[((e0 + i) << 3) + (jg << 2)];
            acc0 = fmaf(xv.x, w[i], acc0);
            acc1 = fmaf(xv.y, w[i], acc1);
            acc2 = fmaf(xv.z, w[i], acc2);
            acc3 = fmaf(xv.w, w[i], acc3);
        }
    }
    float4 x2 = make_float4(silu(acc0), silu(acc1), silu(acc2), silu(acc3));
    __syncthreads();
    *(float4*)&x_lds[(d << 3) + (jg << 2)] = x2;
    __syncthreads();

    float o0 = b3[d], o1 = o0, o2 = o0, o3 = o0;
#pragma unroll
    for (int e0 = 0; e0 < D_PET; e0 += 8) {
        float w[8];
#pragma unroll
        for (int i = 0; i < 8; i++) w[i] = W3[(e0 + i) * D_PET + d];
        __builtin_amdgcn_sched_barrier(0);
#pragma unroll
        for (int i = 0; i < 8; i++) {
            float4 xv = *(const float4*)&x_lds[((e0 + i) << 3) + (jg << 2)];
            o0 = fmaf(xv.x, w[i], o0);
            o1 = fmaf(xv.y, w[i], o1);
            o2 = fmaf(xv.z, w[i], o2);
            o3 = fmaf(xv.w, w[i], o3);
        }
    }
    float out4[4] = {o0, o1, o2, o3};
#pragma unroll
    for (int i = 0; i < 4; i++) {
        int j = jg * 4 + i;
        filt[(size_t)(bk0 + j) * D_PET + d] = out4[i];
    }
}

// ---------------------------------------------------------------------------
// Kernel 2 (v5): register-tiled 4k x 4d outer product.
// grid = 16 b x 8 ktiles x 4 atom-splits = 512 blocks, 256 threads.
// Thread: dq=tid&31 -> d0=dq*4, kq=tid>>5 -> k0=kt*32+kq*4.
// Per atom: 3 loads (h f4, cs 2xf4) -> 32 FMA. 4-atom ping-pong chunks.
// Splits accumulate into zeroed t2 via unsafeAtomicAdd (filt distributes).
// ---------------------------------------------------------------------------
#define S_LOADC(H, C0, C1, base)                                             \
    do {                                                                     \
        _Pragma("unroll")                                                    \
        for (int i_ = 0; i_ < 4; i_++) {                                     \
            int n_ = (base) + i_;                                            \
            H[i_]  = *(const float4*)(hp + (size_t)n_ * D_PET);              \
            C0[i_] = *(const float4*)(cp + (size_t)n_ * (2 * NK));           \
            C1[i_] = *(const float4*)(cp + (size_t)n_ * (2 * NK) + 4);       \
        }                                                                    \
    } while (0)

#define S_FMAC(H, C0, C1)                                                    \
    do {                                                                     \
        _Pragma("unroll")                                                    \
        for (int i_ = 0; i_ < 4; i_++) {                                     \
            float4 hv = H[i_];                                               \
            float4 ca = C0[i_], cb = C1[i_];                                 \
            re[0][0]=fmaf(ca.x,hv.x,re[0][0]); im[0][0]=fmaf(-ca.y,hv.x,im[0][0]); \
            re[0][1]=fmaf(ca.x,hv.y,re[0][1]); im[0][1]=fmaf(-ca.y,hv.y,im[0][1]); \
            re[0][2]=fmaf(ca.x,hv.z,re[0][2]); im[0][2]=fmaf(-ca.y,hv.z,im[0][2]); \
            re[0][3]=fmaf(ca.x,hv.w,re[0][3]); im[0][3]=fmaf(-ca.y,hv.w,im[0][3]); \
            re[1][0]=fmaf(ca.z,hv.x,re[1][0]); im[1][0]=fmaf(-ca.w,hv.x,im[1][0]); \
            re[1][1]=fmaf(ca.z,hv.y,re[1][1]); im[1][1]=fmaf(-ca.w,hv.y,im[1][1]); \
            re[1][2]=fmaf(ca.z,hv.z,re[1][2]); im[1][2]=fmaf(-ca.w,hv.z,im[1][2]); \
            re[1][3]=fmaf(ca.z,hv.w,re[1][3]); im[1][3]=fmaf(-ca.w,hv.w,im[1][3]); \
            re[2][0]=fmaf(cb.x,hv.x,re[2][0]); im[2][0]=fmaf(-cb.y,hv.x,im[2][0]); \
            re[2][1]=fmaf(cb.x,hv.y,re[2][1]); im[2][1]=fmaf(-cb.y,hv.y,im[2][1]); \
            re[2][2]=fmaf(cb.x,hv.z,re[2][2]); im[2][2]=fmaf(-cb.y,hv.z,im[2][2]); \
            re[2][3]=fmaf(cb.x,hv.w,re[2][3]); im[2][3]=fmaf(-cb.y,hv.w,im[2][3]); \
            re[3][0]=fmaf(cb.z,hv.x,re[3][0]); im[3][0]=fmaf(-cb.w,hv.x,im[3][0]); \
            re[3][1]=fmaf(cb.z,hv.y,re[3][1]); im[3][1]=fmaf(-cb.w,hv.y,im[3][1]); \
            re[3][2]=fmaf(cb.z,hv.z,re[3][2]); im[3][2]=fmaf(-cb.w,hv.z,im[3][2]); \
            re[3][3]=fmaf(cb.z,hv.w,re[3][3]); im[3][3]=fmaf(-cb.w,hv.w,im[3][3]); \
        }                                                                    \
    } while (0)

__global__ void __launch_bounds__(256) s_kernel(
                         const float* __restrict__ h,
                         const float* __restrict__ cs2f,
                         const int* __restrict__ batch,
                         const float* __restrict__ filt,
                         float* __restrict__ t2f) {
    int bi = blockIdx.x;
    int v  = (bi & 7) * 64 + (bi >> 3);     // XCD-contiguous, bijective
    int b  = v >> 5;
    int r  = v & 31;
    int kt = r >> 2;
    int sp = r & 3;
    int dq = threadIdx.x & 31;
    int kq = threadIdx.x >> 5;
    int k0 = kt * 32 + kq * 4;
    int d0 = dq * 4;

    int lo = lower_bound_dev(batch, NB, b);
    int hi = lower_bound_dev(batch, NB, b + 1);
    int cnt = hi - lo;
    int a0 = lo + ((cnt * sp) >> 2);
    int a1 = lo + ((cnt * (sp + 1)) >> 2);

    float re[4][4], im[4][4];
#pragma unroll
    for (int i = 0; i < 4; i++)
#pragma unroll
        for (int j = 0; j < 4; j++) { re[i][j] = 0.f; im[i][j] = 0.f; }

    const float* hp = h + d0;
    const float* cp = cs2f + 2 * k0;

    float4 hA[4], cA0[4], cA1[4], hB[4], cB0[4], cB1[4];

    int n = a0;
    if (n + 4 <= a1) {
        S_LOADC(hA, cA0, cA1, n);
        bool inA = true;
        int nn = n + 4;
        for (; nn + 4 <= a1; nn += 4) {
            if (inA) { S_LOADC(hB, cB0, cB1, nn); __builtin_amdgcn_sched_barrier(0); S_FMAC(hA, cA0, cA1); }
            else     { S_LOADC(hA, cA0, cA1, nn); __builtin_amdgcn_sched_barrier(0); S_FMAC(hB, cB0, cB1); }
            inA = !inA;
        }
        __builtin_amdgcn_sched_barrier(0);
        if (inA) { S_FMAC(hA, cA0, cA1); } else { S_FMAC(hB, cB0, cB1); }
        n = nn;
    }
    for (; n < a1; n++) {
        float4 hv = *(const float4*)(hp + (size_t)n * D_PET);
        float4 ca = *(const float4*)(cp + (size_t)n * (2 * NK));
        float4 cb = *(const float4*)(cp + (size_t)n * (2 * NK) + 4);
        float4 hT[1] = {hv}, c0T[1] = {ca}, c1T[1] = {cb};
#pragma unroll
        for (int ki = 0; ki < 4; ki++) {
            float cc = (ki == 0) ? c0T[0].x : (ki == 1) ? c0T[0].z : (ki == 2) ? c1T[0].x : c1T[0].z;
            float ss = (ki == 0) ? c0T[0].y : (ki == 1) ? c0T[0].w : (ki == 2) ? c1T[0].y : c1T[0].w;
            float* hp4 = (float*)&hT[0];
#pragma unroll
            for (int j = 0; j < 4; j++) {
                re[ki][j] = fmaf(cc, hp4[j], re[ki][j]);
                im[ki][j] = fmaf(-ss, hp4[j], im[ki][j]);
            }
        }
    }

    // epilogue: multiply by filt, atomic-accumulate into t2
#pragma unroll
    for (int ki = 0; ki < 4; ki++) {
        size_t row = ((size_t)b * NK + k0 + ki) * D_PET + d0;
        float4 f = *(const float4*)(filt + row);
        float* fp = (float*)&f;
#pragma unroll
        for (int j = 0; j < 4; j++) {
            size_t idx = (row + j) * 2;
            unsafeAtomicAdd(&t2f[idx],     re[ki][j] * fp[j]);
            unsafeAtomicAdd(&t2f[idx + 1], im[ki][j] * fp[j]);
        }
    }
}

// ---------------------------------------------------------------------------
// Kernel 3 (v5): out[n,d] = sum_k e^{+i phi_nk} * t2[batch[n],k,d]
// grid = 256 blocks x 512 threads. Block: 8 atoms x 128 d, k split in half
// across wave-groups. Thread-tile: 2 atoms x 2 d. Per k: 1 shared t float4 +
// broadcast cs -> 16 FMA. 8-k ping-pong chunks (16 loads -> 128 FMA).
// LDS reduction combines the k-halves.
// ---------------------------------------------------------------------------
#define O_LOADC(s, c)                                                        \
    do {                                                                     \
        _Pragma("unroll")                                                    \
        for (int j_ = 0; j_ < 8; j_++)                                       \
            tv[s][j_] = *(const float4*)(tA + (size_t)(kbase + (c) * 8 + j_) * (2 * D_PET)); \
        _Pragma("unroll")                                                    \
        for (int j_ = 0; j_ < 4; j_++) {                                     \
            qa[s][j_] = *(const float4*)(cA + kbase * 2 + (c) * 16 + j_ * 4);\
            qb[s][j_] = *(const float4*)(cB + kbase * 2 + (c) * 16 + j_ * 4);\
        }                                                                    \
    } while (0)

#define O_FMAC(s)                                                            \
    do {                                                                     \
        _Pragma("unroll")                                                    \
        for (int j_ = 0; j_ < 8; j_++) {                                     \
            float4 t = tv[s][j_];                                            \
            float4 q = qa[s][j_ >> 1];                                       \
            float cc = (j_ & 1) ? q.z : q.x;                                 \
            float ss = (j_ & 1) ? q.w : q.y;                                 \
            accAr0 = fmaf(cc, t.x, accAr0); accAr0 = fmaf(-ss, t.y, accAr0); \
            accAi0 = fmaf(cc, t.y, accAi0); accAi0 = fmaf( ss, t.x, accAi0); \
            accAr1 = fmaf(cc, t.z, accAr1); accAr1 = fmaf(-ss, t.w, accAr1); \
            accAi1 = fmaf(cc, t.w, accAi1); accAi1 = fmaf( ss, t.z, accAi1); \
            q = qb[s][j_ >> 1];                                              \
            cc = (j_ & 1) ? q.z : q.x;                                       \
            ss = (j_ & 1) ? q.w : q.y;                                       \
            accBr0 = fmaf(cc, t.x, accBr0); accBr0 = fmaf(-ss, t.y, accBr0); \
            accBi0 = fmaf(cc, t.y, accBi0); accBi0 = fmaf( ss, t.x, accBi0); \
            accBr1 = fmaf(cc, t.z, accBr1); accBr1 = fmaf(-ss, t.w, accBr1); \
            accBi1 = fmaf(cc, t.w, accBi1); accBi1 = fmaf( ss, t.z, accBi1); \
        }                                                                    \
    } while (0)

__global__ void __launch_bounds__(512) out_kernel(
                           const float* __restrict__ cs2f,
                           const int* __restrict__ batch,
                           const float* __restrict__ t2f,
                           float* __restrict__ out, int interleaved) {
    int bi = blockIdx.x;
    int v  = (bi & 7) * 32 + (bi >> 3);     // XCD-contiguous, bijective (256)
    int nb = v * 8;
    int dg = threadIdx.x & 63;
    int w  = threadIdx.x >> 6;              // 0..7
    int ng = w & 3;
    int kh = w >> 2;
    int d0 = dg * 2;
    int n0 = nb + ng * 2, n1 = n0 + 1;
    int kbase = kh * 128;

    int bA = batch[n0], bB = batch[n1];

    const float* tA = t2f + (size_t)bA * NK * (2 * D_PET) + 2 * d0;
    const float* cA = cs2f + (size_t)n0 * (2 * NK);
    const float* cB = cs2f + (size_t)n1 * (2 * NK);

    float accAr0 = 0.f, accAi0 = 0.f, accAr1 = 0.f, accAi1 = 0.f;
    float accBr0 = 0.f, accBi0 = 0.f, accBr1 = 0.f, accBi1 = 0.f;

    if (bA == bB) {
        float4 tv[2][8], qa[2][4], qb[2][4];
        O_LOADC(0, 0);
#pragma unroll
        for (int c = 0; c < 16; c++) {
            if (c + 1 < 16) {
                if (((c + 1) & 1) == 0) { O_LOADC(0, c + 1); } else { O_LOADC(1, c + 1); }
            }
            __builtin_amdgcn_sched_barrier(0);
            if ((c & 1) == 0) { O_FMAC(0); } else { O_FMAC(1); }
        }
    } else {
        // batch boundary inside the atom pair (rare, wave-uniform)
        const float* tB = t2f + (size_t)bB * NK * (2 * D_PET) + 2 * d0;
        for (int c = 0; c < 16; c++) {
            float4 ta[8], tb[8], pa[4], pb[4];
#pragma unroll
            for (int j = 0; j < 8; j++) {
                ta[j] = *(const float4*)(tA + (size_t)(kbase + c * 8 + j) * (2 * D_PET));
                tb[j] = *(const float4*)(tB + (size_t)(kbase + c * 8 + j) * (2 * D_PET));
            }
#pragma unroll
            for (int j = 0; j < 4; j++) {
                pa[j] = *(const float4*)(cA + kbase * 2 + c * 16 + j * 4);
                pb[j] = *(const float4*)(cB + kbase * 2 + c * 16 + j * 4);
            }
            __builtin_amdgcn_sched_barrier(0);
#pragma unroll
            for (int j = 0; j < 8; j++) {
                float4 t = ta[j];
                float4 q = pa[j >> 1];
                float cc = (j & 1) ? q.z : q.x;
                float ss = (j & 1) ? q.w : q.y;
                accAr0 = fmaf(cc, t.x, accAr0); accAr0 = fmaf(-ss, t.y, accAr0);
                accAi0 = fmaf(cc, t.y, accAi0); accAi0 = fmaf( ss, t.x, accAi0);
                accAr1 = fmaf(cc, t.z, accAr1); accAr1 = fmaf(-ss, t.w, accAr1);
                accAi1 = fmaf(cc, t.w, accAi1); accAi1 = fmaf( ss, t.z, accAi1);
                t = tb[j];
                q = pb[j >> 1];
                cc = (j & 1) ? q.z : q.x;
                ss = (j & 1) ? q.w : q.y;
                accBr0 = fmaf(cc, t.x, accBr0); accBr0 = fmaf(-ss, t.y, accBr0);
                accBi0 = fmaf(cc, t.y, accBi0); accBi0 = fmaf( ss, t.x, accBi0);
                accBr1 = fmaf(cc, t.z, accBr1); accBr1 = fmaf(-ss, t.w, accBr1);
                accBi1 = fmaf(cc, t.w, accBi1); accBi1 = fmaf( ss, t.z, accBi1);
            }
        }
    }

    // combine k-halves
    __shared__ float red[4][64][8];
    if (kh == 1) {
        red[ng][dg][0] = accAr0; red[ng][dg][1] = accAi0;
        red[ng][dg][2] = accAr1; red[ng][dg][3] = accAi1;
        red[ng][dg][4] = accBr0; red[ng][dg][5] = accBi0;
        red[ng][dg][6] = accBr1; red[ng][dg][7] = accBi1;
    }
    __syncthreads();
    if (kh == 0) {
        accAr0 += red[ng][dg][0]; accAi0 += red[ng][dg][1];
        accAr1 += red[ng][dg][2]; accAi1 += red[ng][dg][3];
        accBr0 += red[ng][dg][4]; accBi0 += red[ng][dg][5];
        accBr1 += red[ng][dg][6]; accBi1 += red[ng][dg][7];
        if (interleaved) {
            *(float4*)(out + ((size_t)n0 * D_PET + d0) * 2) = make_float4(accAr0, accAi0, accAr1, accAi1);
            *(float4*)(out + ((size_t)n1 * D_PET + d0) * 2) = make_float4(accBr0, accBi0, accBr1, accBi1);
        } else {
            *(float2*)(out + (size_t)n0 * D_PET + d0) = make_float2(accAr0, accAr1);
            *(float2*)(out + (size_t)n1 * D_PET + d0) = make_float2(accBr0, accBr1);
        }
    }
}

// ---------------------------------------------------------------------------
extern "C" void kernel_launch(void* const* d_in, const int* in_sizes, int n_in,
                              void* d_out, int out_size, void* d_ws, size_t ws_size,
                              hipStream_t stream) {
    const float* kvec = (const float*)d_in[0];
    const float* pos  = (const float*)d_in[1];
    const float* h    = (const float*)d_in[2];
    const float* W1   = (const float*)d_in[3];
    const float* b1   = (const float*)d_in[4];
    const float* W2   = (const float*)d_in[5];
    const float* b2   = (const float*)d_in[6];
    const float* W3   = (const float*)d_in[7];
    const float* b3   = (const float*)d_in[8];
    const int*   batch = (const int*)d_in[9];

    float* ws   = (float*)d_ws;
    float* filt = ws;                                    // 512K floats
    float* cs2  = filt + (size_t)NBATCH * NK * D_PET;    // 1M floats
    float* t2f  = cs2 + (size_t)NB * NK * 2;             // 1M floats

    int interleaved = (out_size == NB * D_PET * 2) ? 1 : 0;

    prep_kernel<<<PREP_GRID, 256, 0, stream>>>(kvec, W1, b1, W2, b2, W3, b3,
                                               filt, pos, batch, (float2*)cs2, t2f);
    s_kernel<<<512, 256, 0, stream>>>(h, cs2, batch, filt, t2f);
    out_kernel<<<256, 512, 0, stream>>>(cs2, batch, t2f, (float*)d_out, interleaved);
}

// Round 5
// 140.483 us; speedup vs baseline: 1.9794x; 1.9794x over previous
//
#include <hip/hip_runtime.h>
#include <math.h>

#define D_PET 128
#define NK    256
#define NB    2048
#define NBATCH 16

__device__ __forceinline__ float silu(float x) {
    return x / (1.0f + expf(-x));
}

__device__ __forceinline__ int lower_bound_dev(const int* a, int n, int v) {
    int lo = 0, hi = n;
    while (lo < hi) {
        int m = (lo + hi) >> 1;
        if (a[m] < v) lo = m + 1; else hi = m;
    }
    return lo;
}

// ---------------------------------------------------------------------------
// Kernel 1 (fused): [0,512) MLP blocks, [512,2560) phase blocks.
// ---------------------------------------------------------------------------
#define MJ 8
#define MLP_BLOCKS (NBATCH * NK / MJ)       // 512
#define PREP_GRID (MLP_BLOCKS + NB)

__global__ void __launch_bounds__(256) prep_kernel(
                           const float* __restrict__ kvec,
                           const float* __restrict__ W1, const float* __restrict__ b1,
                           const float* __restrict__ W2, const float* __restrict__ b2,
                           const float* __restrict__ W3, const float* __restrict__ b3,
                           float* __restrict__ filt,
                           const float* __restrict__ pos,
                           const int* __restrict__ batch,
                           float2* __restrict__ cs2) {
    __shared__ float kv_s[MJ * 3];
    __shared__ float x_lds[D_PET * MJ];

    if (blockIdx.x >= MLP_BLOCKS) {
        // ---- phase table ----
        int n = blockIdx.x - MLP_BLOCKS;
        int k = threadIdx.x;
        int b = batch[n];
        float p0 = pos[n * 3 + 0], p1 = pos[n * 3 + 1], p2 = pos[n * 3 + 2];
        const float* kv = kvec + ((size_t)b * NK + k) * 3;
        float ph = p0 * kv[0] + p1 * kv[1] + p2 * kv[2];
        float s, c;
        sincosf(ph, &s, &c);
        cs2[(size_t)n * NK + k] = make_float2(c, s);
        return;
    }

    // ---- MLP ----
    int bk0 = blockIdx.x * MJ;
    int d   = threadIdx.x & (D_PET - 1);
    int jg  = threadIdx.x >> 7;

    if (threadIdx.x < MJ * 3) kv_s[threadIdx.x] = kvec[bk0 * 3 + threadIdx.x];
    __syncthreads();

    float w10 = W1[0 * D_PET + d], w11 = W1[1 * D_PET + d], w12 = W1[2 * D_PET + d];
    float bb1 = b1[d];
    float4 x1;
    {
        float* xp = (float*)&x1;
#pragma unroll
        for (int i = 0; i < 4; i++) {
            int j = jg * 4 + i;
            float a = bb1;
            a = fmaf(kv_s[j * 3 + 0], w10, a);
            a = fmaf(kv_s[j * 3 + 1], w11, a);
            a = fmaf(kv_s[j * 3 + 2], w12, a);
            xp[i] = silu(a);
        }
    }
    *(float4*)&x_lds[(d << 3) + (jg << 2)] = x1;
    __syncthreads();

    float acc0 = b2[d], acc1 = acc0, acc2 = acc0, acc3 = acc0;
#pragma unroll
    for (int e0 = 0; e0 < D_PET; e0 += 8) {
        float w[8];
#pragma unroll
        for (int i = 0; i < 8; i++) w[i] = W2[(e0 + i) * D_PET + d];
        __builtin_amdgcn_sched_barrier(0);
#pragma unroll
        for (int i = 0; i < 8; i++) {
            float4 xv = *(const float4*)&x_lds[((e0 + i) << 3) + (jg << 2)];
            acc0 = fmaf(xv.x, w[i], acc0);
            acc1 = fmaf(xv.y, w[i], acc1);
            acc2 = fmaf(xv.z, w[i], acc2);
            acc3 = fmaf(xv.w, w[i], acc3);
        }
    }
    float4 x2 = make_float4(silu(acc0), silu(acc1), silu(acc2), silu(acc3));
    __syncthreads();
    *(float4*)&x_lds[(d << 3) + (jg << 2)] = x2;
    __syncthreads();

    float o0 = b3[d], o1 = o0, o2 = o0, o3 = o0;
#pragma unroll
    for (int e0 = 0; e0 < D_PET; e0 += 8) {
        float w[8];
#pragma unroll
        for (int i = 0; i < 8; i++) w[i] = W3[(e0 + i) * D_PET + d];
        __builtin_amdgcn_sched_barrier(0);
#pragma unroll
        for (int i = 0; i < 8; i++) {
            float4 xv = *(const float4*)&x_lds[((e0 + i) << 3) + (jg << 2)];
            o0 = fmaf(xv.x, w[i], o0);
            o1 = fmaf(xv.y, w[i], o1);
            o2 = fmaf(xv.z, w[i], o2);
            o3 = fmaf(xv.w, w[i], o3);
        }
    }
    float out4[4] = {o0, o1, o2, o3};
#pragma unroll
    for (int i = 0; i < 4; i++) {
        int j = jg * 4 + i;
        filt[(size_t)(bk0 + j) * D_PET + d] = out4[i];
    }
}

// ---------------------------------------------------------------------------
// Kernel 2 (v6): partial s sums, NO atomics.
// grid = 16 b x 16 ktiles(16k) x 2 atom-splits = 512 blocks, 256 threads.
// Thread: dq=tid&31 -> d0=dq*4; kq=tid>>5 -> k = kt*16+kq*2+{0,1}.
// Per atom: 2 loads (h f4, cs f4) -> 16 FMA. Depth-2 pipeline, 3 buffer sets.
// Split sp writes to its own partial buffer (plain float4 stores).
// ---------------------------------------------------------------------------
#define SLOADN(S, base)                                                      \
    do {                                                                     \
        _Pragma("unroll")                                                    \
        for (int i_ = 0; i_ < 4; i_++) {                                     \
            hb##S[i_] = *(const float4*)(hp + (size_t)((base) + i_) * D_PET);\
            cb##S[i_] = *(const float4*)(cp + (size_t)((base) + i_) * (2 * NK)); \
        }                                                                    \
    } while (0)

#define SFMAN(S)                                                             \
    do {                                                                     \
        _Pragma("unroll")                                                    \
        for (int i_ = 0; i_ < 4; i_++) {                                     \
            float4 hv = hb##S[i_];                                           \
            float4 q  = cb##S[i_];                                           \
            re0[0]=fmaf(q.x,hv.x,re0[0]); im0[0]=fmaf(-q.y,hv.x,im0[0]);     \
            re0[1]=fmaf(q.x,hv.y,re0[1]); im0[1]=fmaf(-q.y,hv.y,im0[1]);     \
            re0[2]=fmaf(q.x,hv.z,re0[2]); im0[2]=fmaf(-q.y,hv.z,im0[2]);     \
            re0[3]=fmaf(q.x,hv.w,re0[3]); im0[3]=fmaf(-q.y,hv.w,im0[3]);     \
            re1[0]=fmaf(q.z,hv.x,re1[0]); im1[0]=fmaf(-q.w,hv.x,im1[0]);     \
            re1[1]=fmaf(q.z,hv.y,re1[1]); im1[1]=fmaf(-q.w,hv.y,im1[1]);     \
            re1[2]=fmaf(q.z,hv.z,re1[2]); im1[2]=fmaf(-q.w,hv.z,im1[2]);     \
            re1[3]=fmaf(q.z,hv.w,re1[3]); im1[3]=fmaf(-q.w,hv.w,im1[3]);     \
        }                                                                    \
    } while (0)

__global__ void __launch_bounds__(256) s_kernel(
                         const float* __restrict__ h,
                         const float* __restrict__ cs2f,
                         const int* __restrict__ batch,
                         float* __restrict__ sp0buf,
                         float* __restrict__ sp1buf) {
    int bi = blockIdx.x;
    int v  = (bi & 7) * 64 + (bi >> 3);     // XCD-contiguous, bijective (512)
    int b  = v >> 5;
    int r  = v & 31;
    int kt = r >> 1;
    int sp = r & 1;
    int dq = threadIdx.x & 31;
    int kq = threadIdx.x >> 5;              // 0..7
    int k0 = kt * 16 + kq * 2;
    int d0 = dq * 4;

    int lo = lower_bound_dev(batch, NB, b);
    int hi = lower_bound_dev(batch, NB, b + 1);
    int cnt = hi - lo;
    int a0 = lo + ((cnt * sp) >> 1);
    int a1 = lo + ((cnt * (sp + 1)) >> 1);

    float re0[4] = {0.f,0.f,0.f,0.f}, im0[4] = {0.f,0.f,0.f,0.f};
    float re1[4] = {0.f,0.f,0.f,0.f}, im1[4] = {0.f,0.f,0.f,0.f};

    const float* hp = h + d0;
    const float* cp = cs2f + 2 * k0;

    float4 hb0[4], hb1[4], hb2[4];
    float4 cb0[4], cb1[4], cb2[4];

    int n = a0;
    int nch = (a1 - a0) >> 2;
    if (nch >= 2) {
        SLOADN(0, n); SLOADN(1, n + 4);
        int c = 0;
        for (; c + 5 <= nch; c += 3) {
            SLOADN(2, n + (c + 2) * 4); __builtin_amdgcn_sched_barrier(0); SFMAN(0);
            SLOADN(0, n + (c + 3) * 4); __builtin_amdgcn_sched_barrier(0); SFMAN(1);
            SLOADN(1, n + (c + 4) * 4); __builtin_amdgcn_sched_barrier(0); SFMAN(2);
        }
        int rr = nch - c;   // 2, 3, or 4
        if (rr == 2) {
            __builtin_amdgcn_sched_barrier(0); SFMAN(0); SFMAN(1);
        } else if (rr == 3) {
            SLOADN(2, n + (c + 2) * 4); __builtin_amdgcn_sched_barrier(0);
            SFMAN(0); SFMAN(1); SFMAN(2);
        } else {
            SLOADN(2, n + (c + 2) * 4); __builtin_amdgcn_sched_barrier(0); SFMAN(0);
            SLOADN(0, n + (c + 3) * 4); __builtin_amdgcn_sched_barrier(0); SFMAN(1);
            SFMAN(2); SFMAN(0);
        }
        n += nch * 4;
    }
    for (; n < a1; n++) {
        float4 hv = *(const float4*)(hp + (size_t)n * D_PET);
        float4 q  = *(const float4*)(cp + (size_t)n * (2 * NK));
        re0[0]=fmaf(q.x,hv.x,re0[0]); im0[0]=fmaf(-q.y,hv.x,im0[0]);
        re0[1]=fmaf(q.x,hv.y,re0[1]); im0[1]=fmaf(-q.y,hv.y,im0[1]);
        re0[2]=fmaf(q.x,hv.z,re0[2]); im0[2]=fmaf(-q.y,hv.z,im0[2]);
        re0[3]=fmaf(q.x,hv.w,re0[3]); im0[3]=fmaf(-q.y,hv.w,im0[3]);
        re1[0]=fmaf(q.z,hv.x,re1[0]); im1[0]=fmaf(-q.w,hv.x,im1[0]);
        re1[1]=fmaf(q.z,hv.y,re1[1]); im1[1]=fmaf(-q.w,hv.y,im1[1]);
        re1[2]=fmaf(q.z,hv.z,re1[2]); im1[2]=fmaf(-q.w,hv.z,im1[2]);
        re1[3]=fmaf(q.z,hv.w,re1[3]); im1[3]=fmaf(-q.w,hv.w,im1[3]);
    }

    float* dst = sp ? sp1buf : sp0buf;
    size_t base0 = ((size_t)b * NK + k0) * D_PET + d0;        // in elements
    // k = k0: elements (re,im) interleaved
    *(float4*)(dst + base0 * 2)     = make_float4(re0[0], im0[0], re0[1], im0[1]);
    *(float4*)(dst + base0 * 2 + 4) = make_float4(re0[2], im0[2], re0[3], im0[3]);
    size_t base1 = base0 + D_PET;
    *(float4*)(dst + base1 * 2)     = make_float4(re1[0], im1[0], re1[1], im1[1]);
    *(float4*)(dst + base1 * 2 + 4) = make_float4(re1[2], im1[2], re1[3], im1[3]);
}

// ---------------------------------------------------------------------------
// Kernel 3 (v6): out[n,d] = sum_k e^{+i phi_nk} * (sp0+sp1)[b,k,d]*filt[b,k,d]
// grid = 256 blocks x 512 threads. Block: 8 atoms x 128 d, k halved across
// wave-groups. Thread: 2 atoms x 2 d x 128 k. 4k chunks, depth-2 pipeline,
// 3 named buffer sets. LDS reduction combines k-halves.
// ---------------------------------------------------------------------------
#define OLOADN(S, C)                                                         \
    do {                                                                     \
        _Pragma("unroll")                                                    \
        for (int j_ = 0; j_ < 4; j_++) {                                     \
            int k_ = kbase + (C) * 4 + j_;                                   \
            p0_##S[j_] = *(const float4*)(t0p + (size_t)k_ * (2 * D_PET));   \
            p1_##S[j_] = *(const float4*)(t1p + (size_t)k_ * (2 * D_PET));   \
            fv_##S[j_] = *(const float2*)(fp  + (size_t)k_ * D_PET);         \
        }                                                                    \
        _Pragma("unroll")                                                    \
        for (int j_ = 0; j_ < 2; j_++) {                                     \
            qa_##S[j_] = *(const float4*)(cA + 2 * kbase + (C) * 8 + j_ * 4);\
            qb_##S[j_] = *(const float4*)(cB + 2 * kbase + (C) * 8 + j_ * 4);\
        }                                                                    \
    } while (0)

#define OFMAN(S)                                                             \
    do {                                                                     \
        _Pragma("unroll")                                                    \
        for (int j_ = 0; j_ < 4; j_++) {                                     \
            float4 u0 = p0_##S[j_], u1 = p1_##S[j_];                         \
            float2 f  = fv_##S[j_];                                          \
            float tr0 = (u0.x + u1.x) * f.x, ti0 = (u0.y + u1.y) * f.x;      \
            float tr1 = (u0.z + u1.z) * f.y, ti1 = (u0.w + u1.w) * f.y;      \
            float4 q = qa_##S[j_ >> 1];                                      \
            float cc = (j_ & 1) ? q.z : q.x, ss = (j_ & 1) ? q.w : q.y;      \
            aAr0 = fmaf(cc, tr0, aAr0); aAr0 = fmaf(-ss, ti0, aAr0);         \
            aAi0 = fmaf(cc, ti0, aAi0); aAi0 = fmaf( ss, tr0, aAi0);         \
            aAr1 = fmaf(cc, tr1, aAr1); aAr1 = fmaf(-ss, ti1, aAr1);         \
            aAi1 = fmaf(cc, ti1, aAi1); aAi1 = fmaf( ss, tr1, aAi1);         \
            q = qb_##S[j_ >> 1];                                             \
            cc = (j_ & 1) ? q.z : q.x; ss = (j_ & 1) ? q.w : q.y;            \
            aBr0 = fmaf(cc, tr0, aBr0); aBr0 = fmaf(-ss, ti0, aBr0);         \
            aBi0 = fmaf(cc, ti0, aBi0); aBi0 = fmaf( ss, tr0, aBi0);         \
            aBr1 = fmaf(cc, tr1, aBr1); aBr1 = fmaf(-ss, ti1, aBr1);         \
            aBi1 = fmaf(cc, ti1, aBi1); aBi1 = fmaf( ss, tr1, aBi1);         \
        }                                                                    \
    } while (0)

__global__ void __launch_bounds__(512) out_kernel(
                           const float* __restrict__ cs2f,
                           const int* __restrict__ batch,
                           const float* __restrict__ sp0buf,
                           const float* __restrict__ sp1buf,
                           const float* __restrict__ filt,
                           float* __restrict__ out, int interleaved) {
    int bi = blockIdx.x;
    int v  = (bi & 7) * 32 + (bi >> 3);     // XCD-contiguous, bijective (256)
    int nb = v * 8;
    int dg = threadIdx.x & 63;
    int w  = threadIdx.x >> 6;              // 0..7
    int ng = w & 3;
    int kh = w >> 2;
    int d0 = dg * 2;
    int n0 = nb + ng * 2, n1 = n0 + 1;
    int kbase = kh * 128;

    int bA = batch[n0], bB = batch[n1];

    const float* cA = cs2f + (size_t)n0 * (2 * NK);
    const float* cB = cs2f + (size_t)n1 * (2 * NK);

    float aAr0 = 0.f, aAi0 = 0.f, aAr1 = 0.f, aAi1 = 0.f;
    float aBr0 = 0.f, aBi0 = 0.f, aBr1 = 0.f, aBi1 = 0.f;

    if (bA == bB) {
        const float* t0p = sp0buf + ((size_t)bA * NK * D_PET + d0) * 2;
        const float* t1p = sp1buf + ((size_t)bA * NK * D_PET + d0) * 2;
        const float* fp  = filt   +  (size_t)bA * NK * D_PET + d0;

        float4 p0_0[4], p0_1[4], p0_2[4];
        float4 p1_0[4], p1_1[4], p1_2[4];
        float2 fv_0[4], fv_1[4], fv_2[4];
        float4 qa_0[2], qa_1[2], qa_2[2];
        float4 qb_0[2], qb_1[2], qb_2[2];

        OLOADN(0, 0); OLOADN(1, 1);
#pragma unroll
        for (int c = 0; c < 30; c += 3) {
            OLOADN(2, c + 2); __builtin_amdgcn_sched_barrier(0); OFMAN(0);
            OLOADN(0, c + 3); __builtin_amdgcn_sched_barrier(0); OFMAN(1);
            OLOADN(1, c + 4); __builtin_amdgcn_sched_barrier(0); OFMAN(2);
        }
        // chunks 30 (slot 0), 31 (slot 1) already loaded
        __builtin_amdgcn_sched_barrier(0);
        OFMAN(0); OFMAN(1);
    } else {
        // batch boundary inside the atom pair (rare, wave-uniform)
        const float* t0A = sp0buf + ((size_t)bA * NK * D_PET + d0) * 2;
        const float* t1A = sp1buf + ((size_t)bA * NK * D_PET + d0) * 2;
        const float* fA  = filt   +  (size_t)bA * NK * D_PET + d0;
        const float* t0B = sp0buf + ((size_t)bB * NK * D_PET + d0) * 2;
        const float* t1B = sp1buf + ((size_t)bB * NK * D_PET + d0) * 2;
        const float* fB  = filt   +  (size_t)bB * NK * D_PET + d0;
        for (int k = kbase; k < kbase + 128; k += 2) {
            float4 qA = *(const float4*)(cA + 2 * k);
            float4 qB = *(const float4*)(cB + 2 * k);
#pragma unroll
            for (int kk = 0; kk < 2; kk++) {
                int kidx = k + kk;
                float4 uA0 = *(const float4*)(t0A + (size_t)kidx * (2 * D_PET));
                float4 uA1 = *(const float4*)(t1A + (size_t)kidx * (2 * D_PET));
                float2 ffA = *(const float2*)(fA  + (size_t)kidx * D_PET);
                float4 uB0 = *(const float4*)(t0B + (size_t)kidx * (2 * D_PET));
                float4 uB1 = *(const float4*)(t1B + (size_t)kidx * (2 * D_PET));
                float2 ffB = *(const float2*)(fB  + (size_t)kidx * D_PET);
                float trA0 = (uA0.x + uA1.x) * ffA.x, tiA0 = (uA0.y + uA1.y) * ffA.x;
                float trA1 = (uA0.z + uA1.z) * ffA.y, tiA1 = (uA0.w + uA1.w) * ffA.y;
                float trB0 = (uB0.x + uB1.x) * ffB.x, tiB0 = (uB0.y + uB1.y) * ffB.x;
                float trB1 = (uB0.z + uB1.z) * ffB.y, tiB1 = (uB0.w + uB1.w) * ffB.y;
                float cc = kk ? qA.z : qA.x, ss = kk ? qA.w : qA.y;
                aAr0 = fmaf(cc, trA0, aAr0); aAr0 = fmaf(-ss, tiA0, aAr0);
                aAi0 = fmaf(cc, tiA0, aAi0); aAi0 = fmaf( ss, trA0, aAi0);
                aAr1 = fmaf(cc, trA1, aAr1); aAr1 = fmaf(-ss, tiA1, aAr1);
                aAi1 = fmaf(cc, tiA1, aAi1); aAi1 = fmaf( ss, trA1, aAi1);
                cc = kk ? qB.z : qB.x; ss = kk ? qB.w : qB.y;
                aBr0 = fmaf(cc, trB0, aBr0); aBr0 = fmaf(-ss, tiB0, aBr0);
                aBi0 = fmaf(cc, tiB0, aBi0); aBi0 = fmaf( ss, trB0, aBi0);
                aBr1 = fmaf(cc, trB1, aBr1); aBr1 = fmaf(-ss, tiB1, aBr1);
                aBi1 = fmaf(cc, tiB1, aBi1); aBi1 = fmaf( ss, trB1, aBi1);
            }
        }
    }

    // combine k-halves
    __shared__ float red[4][64][8];
    if (kh == 1) {
        red[ng][dg][0] = aAr0; red[ng][dg][1] = aAi0;
        red[ng][dg][2] = aAr1; red[ng][dg][3] = aAi1;
        red[ng][dg][4] = aBr0; red[ng][dg][5] = aBi0;
        red[ng][dg][6] = aBr1; red[ng][dg][7] = aBi1;
    }
    __syncthreads();
    if (kh == 0) {
        aAr0 += red[ng][dg][0]; aAi0 += red[ng][dg][1];
        aAr1 += red[ng][dg][2]; aAi1 += red[ng][dg][3];
        aBr0 += red[ng][dg][4]; aBi0 += red[ng][dg][5];
        aBr1 += red[ng][dg][6]; aBi1 += red[ng][dg][7];
        if (interleaved) {
            *(float4*)(out + ((size_t)n0 * D_PET + d0) * 2) = make_float4(aAr0, aAi0, aAr1, aAi1);
            *(float4*)(out + ((size_t)n1 * D_PET + d0) * 2) = make_float4(aBr0, aBi0, aBr1, aBi1);
        } else {
            *(float2*)(out + (size_t)n0 * D_PET + d0) = make_float2(aAr0, aAr1);
            *(float2*)(out + (size_t)n1 * D_PET + d0) = make_float2(aBr0, aBr1);
        }
    }
}

// ---------------------------------------------------------------------------
extern "C" void kernel_launch(void* const* d_in, const int* in_sizes, int n_in,
                              void* d_out, int out_size, void* d_ws, size_t ws_size,
                              hipStream_t stream) {
    const float* kvec = (const float*)d_in[0];
    const float* pos  = (const float*)d_in[1];
    const float* h    = (const float*)d_in[2];
    const float* W1   = (const float*)d_in[3];
    const float* b1   = (const float*)d_in[4];
    const float* W2   = (const float*)d_in[5];
    const float* b2   = (const float*)d_in[6];
    const float* W3   = (const float*)d_in[7];
    const float* b3   = (const float*)d_in[8];
    const int*   batch = (const int*)d_in[9];

    float* ws   = (float*)d_ws;
    float* filt = ws;                                    // 512K floats (2 MB)
    float* cs2  = filt + (size_t)NBATCH * NK * D_PET;    // 1M floats (4 MB)
    float* sp0  = cs2 + (size_t)NB * NK * 2;             // 1M floats (4 MB)
    float* sp1  = sp0 + (size_t)NBATCH * NK * D_PET * 2; // 1M floats (4 MB)

    int interleaved = (out_size == NB * D_PET * 2) ? 1 : 0;

    prep_kernel<<<PREP_GRID, 256, 0, stream>>>(kvec, W1, b1, W2, b2, W3, b3,
                                               filt, pos, batch, (float2*)cs2);
    s_kernel<<<512, 256, 0, stream>>>(h, cs2, batch, sp0, sp1);
    out_kernel<<<256, 512, 0, stream>>>(cs2, batch, sp0, sp1, filt,
                                        (float*)d_out, interleaved);
}

// Round 6
// 131.593 us; speedup vs baseline: 2.1131x; 1.0676x over previous
//
#include <hip/hip_runtime.h>
#include <math.h>

#define D_PET 128
#define NK    256
#define NB    2048
#define NBATCH 16

__device__ __forceinline__ float silu(float x) {
    return x / (1.0f + expf(-x));
}

__device__ __forceinline__ int lower_bound_dev(const int* a, int n, int v) {
    int lo = 0, hi = n;
    while (lo < hi) {
        int m = (lo + hi) >> 1;
        if (a[m] < v) lo = m + 1; else hi = m;
    }
    return lo;
}

// ---------------------------------------------------------------------------
// Kernel A (fused): blocks [0,512) = s-partial blocks (on-the-fly phases via
// LDS staging, write ts WITHOUT filt), blocks [512,1024) = MLP -> filt.
// The two halves are independent (s: kvec,pos,h,batch ; mlp: kvec,W*).
// ---------------------------------------------------------------------------
#define S_BLOCKS 512
#define MJ 8

// s atom-chunk: 4 atoms -> 4 h float4 loads + 4 LDS float2 reads -> 32 FMA
#define SLOAD(S, c0)                                                         \
    do {                                                                     \
        _Pragma("unroll")                                                    \
        for (int i_ = 0; i_ < 4; i_++) {                                     \
            int a_ = (c0) * 4 + i_;                                          \
            hb##S[i_] = *(const float4*)(hp + (size_t)(base + a_) * D_PET);  \
            cb##S[i_] = cs[a_ * 8 + kq];                                     \
        }                                                                    \
    } while (0)

#define SFMA(S)                                                              \
    do {                                                                     \
        _Pragma("unroll")                                                    \
        for (int i_ = 0; i_ < 4; i_++) {                                     \
            float4 hv = hb##S[i_]; float2 q = cb##S[i_];                     \
            re[0]=fmaf(q.x,hv.x,re[0]); im[0]=fmaf(-q.y,hv.x,im[0]);         \
            re[1]=fmaf(q.x,hv.y,re[1]); im[1]=fmaf(-q.y,hv.y,im[1]);         \
            re[2]=fmaf(q.x,hv.z,re[2]); im[2]=fmaf(-q.y,hv.z,im[2]);         \
            re[3]=fmaf(q.x,hv.w,re[3]); im[3]=fmaf(-q.y,hv.w,im[3]);         \
        }                                                                    \
    } while (0)

__global__ void __launch_bounds__(256) smlp_kernel(
                           const float* __restrict__ kvec,
                           const float* __restrict__ pos,
                           const float* __restrict__ h,
                           const int* __restrict__ batch,
                           const float* __restrict__ W1, const float* __restrict__ b1,
                           const float* __restrict__ W2, const float* __restrict__ b2,
                           const float* __restrict__ W3, const float* __restrict__ b3,
                           float* __restrict__ filt,
                           float* __restrict__ ts) {
    __shared__ float smem[24 + 2048];   // s: kv[8][3] + cs[128][8] f2 ; mlp: kv + x_lds

    if (blockIdx.x < S_BLOCKS) {
        // ---- s-partial: block = (b, kt of 8 k) ----
        int bi = blockIdx.x;
        int v  = (bi & 7) * 64 + (bi >> 3);   // XCD-contiguous: 2 batches/XCD
        int b  = v >> 5;
        int kt = v & 31;
        int dq = threadIdx.x & 31;
        int kq = threadIdx.x >> 5;            // 0..7
        int k  = kt * 8 + kq;
        int d0 = dq * 4;

        float*  kv_s = smem;                  // [8][3]
        float2* cs   = (float2*)(smem + 24);  // [128][8]

        if (threadIdx.x < 24)
            kv_s[threadIdx.x] = kvec[((size_t)b * NK + kt * 8) * 3 + threadIdx.x];

        int lo = lower_bound_dev(batch, NB, b);
        int hi = lower_bound_dev(batch, NB, b + 1);

        float re[4] = {0.f,0.f,0.f,0.f}, im[4] = {0.f,0.f,0.f,0.f};
        const float* hp = h + d0;

        for (int base = lo; base < hi; base += 128) {
            int m = hi - base; if (m > 128) m = 128;
            __syncthreads();   // kv_s ready (1st iter) / prev chunk reads done
            // stage phases for this atom chunk: 4 (atom,k) pairs per thread
#pragma unroll
            for (int i = 0; i < 4; i++) {
                int p = threadIdx.x * 4 + i;
                int a = p >> 3, kk = p & 7;
                if (a < m) {
                    int n = base + a;
                    float ph = pos[n*3+0]*kv_s[kk*3+0]
                             + pos[n*3+1]*kv_s[kk*3+1]
                             + pos[n*3+2]*kv_s[kk*3+2];
                    float sv, cv; sincosf(ph, &sv, &cv);
                    cs[a * 8 + kk] = make_float2(cv, sv);
                }
            }
            __syncthreads();

            float4 hb0[4], hb1[4];
            float2 cb0[4], cb1[4];
            int nch = m >> 2;
            if (nch) {
                SLOAD(0, 0);
                int c = 1;
                for (; c + 1 < nch; c += 2) {
                    SLOAD(1, c);     __builtin_amdgcn_sched_barrier(0); SFMA(0);
                    SLOAD(0, c + 1); __builtin_amdgcn_sched_barrier(0); SFMA(1);
                }
                if (c < nch) {
                    SLOAD(1, c); __builtin_amdgcn_sched_barrier(0);
                    SFMA(0); SFMA(1);
                } else {
                    __builtin_amdgcn_sched_barrier(0); SFMA(0);
                }
            }
            for (int a = nch * 4; a < m; a++) {
                float4 hv = *(const float4*)(hp + (size_t)(base + a) * D_PET);
                float2 q  = cs[a * 8 + kq];
                re[0]=fmaf(q.x,hv.x,re[0]); im[0]=fmaf(-q.y,hv.x,im[0]);
                re[1]=fmaf(q.x,hv.y,re[1]); im[1]=fmaf(-q.y,hv.y,im[1]);
                re[2]=fmaf(q.x,hv.z,re[2]); im[2]=fmaf(-q.y,hv.z,im[2]);
                re[3]=fmaf(q.x,hv.w,re[3]); im[3]=fmaf(-q.y,hv.w,im[3]);
            }
        }

        size_t o = (((size_t)b * NK + k) * D_PET + d0) * 2;
        *(float4*)(ts + o)     = make_float4(re[0], im[0], re[1], im[1]);
        *(float4*)(ts + o + 4) = make_float4(re[2], im[2], re[3], im[3]);
        return;
    }

    // ---- MLP: filt[b,k,:] ----
    int bk0 = (blockIdx.x - S_BLOCKS) * MJ;
    int d   = threadIdx.x & (D_PET - 1);
    int jg  = threadIdx.x >> 7;

    float* kv_s  = smem;          // [MJ*3]
    float* x_lds = smem + 24;     // [D_PET*MJ]

    if (threadIdx.x < MJ * 3) kv_s[threadIdx.x] = kvec[bk0 * 3 + threadIdx.x];
    __syncthreads();

    float w10 = W1[0 * D_PET + d], w11 = W1[1 * D_PET + d], w12 = W1[2 * D_PET + d];
    float bb1 = b1[d];
    float4 x1;
    {
        float* xp = (float*)&x1;
#pragma unroll
        for (int i = 0; i < 4; i++) {
            int j = jg * 4 + i;
            float a = bb1;
            a = fmaf(kv_s[j * 3 + 0], w10, a);
            a = fmaf(kv_s[j * 3 + 1], w11, a);
            a = fmaf(kv_s[j * 3 + 2], w12, a);
            xp[i] = silu(a);
        }
    }
    *(float4*)&x_lds[(d << 3) + (jg << 2)] = x1;
    __syncthreads();

    float acc0 = b2[d], acc1 = acc0, acc2 = acc0, acc3 = acc0;
#pragma unroll
    for (int e0 = 0; e0 < D_PET; e0 += 8) {
        float w[8];
#pragma unroll
        for (int i = 0; i < 8; i++) w[i] = W2[(e0 + i) * D_PET + d];
        __builtin_amdgcn_sched_barrier(0);
#pragma unroll
        for (int i = 0; i < 8; i++) {
            float4 xv = *(const float4*)&x_lds[((e0 + i) << 3) + (jg << 2)];
            acc0 = fmaf(xv.x, w[i], acc0);
            acc1 = fmaf(xv.y, w[i], acc1);
            acc2 = fmaf(xv.z, w[i], acc2);
            acc3 = fmaf(xv.w, w[i], acc3);
        }
    }
    float4 x2 = make_float4(silu(acc0), silu(acc1), silu(acc2), silu(acc3));
    __syncthreads();
    *(float4*)&x_lds[(d << 3) + (jg << 2)] = x2;
    __syncthreads();

    float o0 = b3[d], o1 = o0, o2 = o0, o3 = o0;
#pragma unroll
    for (int e0 = 0; e0 < D_PET; e0 += 8) {
        float w[8];
#pragma unroll
        for (int i = 0; i < 8; i++) w[i] = W3[(e0 + i) * D_PET + d];
        __builtin_amdgcn_sched_barrier(0);
#pragma unroll
        for (int i = 0; i < 8; i++) {
            float4 xv = *(const float4*)&x_lds[((e0 + i) << 3) + (jg << 2)];
            o0 = fmaf(xv.x, w[i], o0);
            o1 = fmaf(xv.y, w[i], o1);
            o2 = fmaf(xv.z, w[i], o2);
            o3 = fmaf(xv.w, w[i], o3);
        }
    }
    float out4[4] = {o0, o1, o2, o3};
#pragma unroll
    for (int i = 0; i < 4; i++) {
        int j = jg * 4 + i;
        filt[(size_t)(bk0 + j) * D_PET + d] = out4[i];
    }
}

// ---------------------------------------------------------------------------
// Kernel B: out[n,d] = sum_k e^{+i phi_nk} * ts[b,k,d]*filt[b,k,d]
// grid = 512 blocks x 512 threads. Block = 4 atoms x 128 d, k in quarters
// across wave-groups (kh), thread = 2 atoms x 2 d x 64 k. Phases staged in
// LDS (on-the-fly sincos, 2/thread). 2-k chunks: 8 global loads + 4 LDS
// reads -> 48 VALU. 2-set pipeline. 4-way LDS reduce over k-quarters.
// ---------------------------------------------------------------------------
#define OLOAD(S, c)                                                          \
    do {                                                                     \
        _Pragma("unroll")                                                    \
        for (int j_ = 0; j_ < 2; j_++) {                                     \
            int k_ = k0 + (c) * 2 + j_;                                      \
            tA_##S[j_] = *(const float4*)(tA + (size_t)k_ * (2 * D_PET));    \
            tB_##S[j_] = *(const float4*)(tB + (size_t)k_ * (2 * D_PET));    \
            fA_##S[j_] = *(const float2*)(fA + (size_t)k_ * D_PET);          \
            fB_##S[j_] = *(const float2*)(fB + (size_t)k_ * D_PET);          \
            qA_##S[j_] = csA[k_]; qB_##S[j_] = csB[k_];                      \
        }                                                                    \
    } while (0)

#define OFMA(S)                                                              \
    do {                                                                     \
        _Pragma("unroll")                                                    \
        for (int j_ = 0; j_ < 2; j_++) {                                     \
            float4 u = tA_##S[j_]; float2 f = fA_##S[j_]; float2 q = qA_##S[j_]; \
            float tr0 = u.x*f.x, ti0 = u.y*f.x, tr1 = u.z*f.y, ti1 = u.w*f.y;\
            aAr0 = fmaf(q.x,tr0,aAr0); aAr0 = fmaf(-q.y,ti0,aAr0);           \
            aAi0 = fmaf(q.x,ti0,aAi0); aAi0 = fmaf( q.y,tr0,aAi0);           \
            aAr1 = fmaf(q.x,tr1,aAr1); aAr1 = fmaf(-q.y,ti1,aAr1);           \
            aAi1 = fmaf(q.x,ti1,aAi1); aAi1 = fmaf( q.y,tr1,aAi1);           \
            u = tB_##S[j_]; f = fB_##S[j_]; q = qB_##S[j_];                  \
            tr0 = u.x*f.x; ti0 = u.y*f.x; tr1 = u.z*f.y; ti1 = u.w*f.y;      \
            aBr0 = fmaf(q.x,tr0,aBr0); aBr0 = fmaf(-q.y,ti0,aBr0);           \
            aBi0 = fmaf(q.x,ti0,aBi0); aBi0 = fmaf( q.y,tr0,aBi0);           \
            aBr1 = fmaf(q.x,tr1,aBr1); aBr1 = fmaf(-q.y,ti1,aBr1);           \
            aBi1 = fmaf(q.x,ti1,aBi1); aBi1 = fmaf( q.y,tr1,aBi1);           \
        }                                                                    \
    } while (0)

__global__ void __launch_bounds__(512) out_kernel(
                           const float* __restrict__ kvec,
                           const float* __restrict__ pos,
                           const int* __restrict__ batch,
                           const float* __restrict__ ts,
                           const float* __restrict__ filt,
                           float* __restrict__ out, int interleaved) {
    __shared__ float2 cs[4 * 256];          // 8 KB phases
    __shared__ float  red[3][2][64][8];     // 12 KB k-quarter reduce

    int bi = blockIdx.x;
    int v  = (bi & 7) * 64 + (bi >> 3);     // XCD-contiguous: 2 batches/XCD
    int nb = v * 4;
    int dg = threadIdx.x & 63;
    int w  = threadIdx.x >> 6;              // 0..7
    int ng = w & 1;                         // atom pair
    int kh = w >> 1;                        // k quarter
    int d0 = dg * 2;
    int k0 = kh * 64;

    // stage phases: 2 (atom,k) pairs per thread
#pragma unroll
    for (int i = 0; i < 2; i++) {
        int p = threadIdx.x * 2 + i;
        int a = p >> 8, k = p & 255;
        int n = nb + a;
        int b = batch[n];
        const float* kv = kvec + ((size_t)b * NK + k) * 3;
        float ph = pos[n*3+0]*kv[0] + pos[n*3+1]*kv[1] + pos[n*3+2]*kv[2];
        float sv, cv; sincosf(ph, &sv, &cv);
        cs[a * 256 + k] = make_float2(cv, sv);
    }
    __syncthreads();

    int nA = nb + ng * 2, nB = nA + 1;
    int bA = batch[nA], bB = batch[nB];
    const float*  tA  = ts   + ((size_t)bA * NK * D_PET + d0) * 2;
    const float*  tB  = ts   + ((size_t)bB * NK * D_PET + d0) * 2;
    const float*  fA  = filt +  (size_t)bA * NK * D_PET + d0;
    const float*  fB  = filt +  (size_t)bB * NK * D_PET + d0;
    const float2* csA = cs + (ng * 2) * 256;
    const float2* csB = csA + 256;

    float aAr0=0.f, aAi0=0.f, aAr1=0.f, aAi1=0.f;
    float aBr0=0.f, aBi0=0.f, aBr1=0.f, aBi1=0.f;

    float4 tA_0[2], tA_1[2], tB_0[2], tB_1[2];
    float2 fA_0[2], fA_1[2], fB_0[2], fB_1[2];
    float2 qA_0[2], qA_1[2], qB_0[2], qB_1[2];

    OLOAD(0, 0);
#pragma unroll
    for (int c = 1; c + 1 < 32; c += 2) {
        OLOAD(1, c);     __builtin_amdgcn_sched_barrier(0); OFMA(0);
        OLOAD(0, c + 1); __builtin_amdgcn_sched_barrier(0); OFMA(1);
    }
    OLOAD(1, 31); __builtin_amdgcn_sched_barrier(0); OFMA(0); OFMA(1);

    // combine k-quarters
    if (kh > 0) {
        float* r = red[kh - 1][ng][dg];
        *(float4*)&r[0] = make_float4(aAr0, aAi0, aAr1, aAi1);
        *(float4*)&r[4] = make_float4(aBr0, aBi0, aBr1, aBi1);
    }
    __syncthreads();
    if (kh == 0) {
#pragma unroll
        for (int q_ = 0; q_ < 3; q_++) {
            const float* r = red[q_][ng][dg];
            aAr0 += r[0]; aAi0 += r[1]; aAr1 += r[2]; aAi1 += r[3];
            aBr0 += r[4]; aBi0 += r[5]; aBr1 += r[6]; aBi1 += r[7];
        }
        if (interleaved) {
            *(float4*)(out + ((size_t)nA * D_PET + d0) * 2) = make_float4(aAr0, aAi0, aAr1, aAi1);
            *(float4*)(out + ((size_t)nB * D_PET + d0) * 2) = make_float4(aBr0, aBi0, aBr1, aBi1);
        } else {
            *(float2*)(out + (size_t)nA * D_PET + d0) = make_float2(aAr0, aAr1);
            *(float2*)(out + (size_t)nB * D_PET + d0) = make_float2(aBr0, aBr1);
        }
    }
}

// ---------------------------------------------------------------------------
extern "C" void kernel_launch(void* const* d_in, const int* in_sizes, int n_in,
                              void* d_out, int out_size, void* d_ws, size_t ws_size,
                              hipStream_t stream) {
    const float* kvec = (const float*)d_in[0];
    const float* pos  = (const float*)d_in[1];
    const float* h    = (const float*)d_in[2];
    const float* W1   = (const float*)d_in[3];
    const float* b1   = (const float*)d_in[4];
    const float* W2   = (const float*)d_in[5];
    const float* b2   = (const float*)d_in[6];
    const float* W3   = (const float*)d_in[7];
    const float* b3   = (const float*)d_in[8];
    const int*   batch = (const int*)d_in[9];

    float* ws   = (float*)d_ws;
    float* filt = ws;                                    // 512K floats (2 MB)
    float* ts   = filt + (size_t)NBATCH * NK * D_PET;    // 1M floats (4 MB)

    int interleaved = (out_size == NB * D_PET * 2) ? 1 : 0;

    smlp_kernel<<<1024, 256, 0, stream>>>(kvec, pos, h, batch,
                                          W1, b1, W2, b2, W3, b3, filt, ts);
    out_kernel<<<512, 512, 0, stream>>>(kvec, pos, batch, ts, filt,
                                        (float*)d_out, interleaved);
}